// Round 2
// baseline (1200.546 us; speedup 1.0000x reference)
//
#include <hip/hip_runtime.h>
#include <hip/hip_bf16.h>
#include <stdint.h>

typedef __attribute__((ext_vector_type(8))) short bf16x8;
typedef __attribute__((ext_vector_type(4))) float f32x4;

#define NT 256

// ---------------- helpers ----------------

__device__ __forceinline__ unsigned bfpack2(float lo, float hi) {
    unsigned ul = __float_as_uint(lo);
    unsigned uh = __float_as_uint(hi);
    ul = (ul + 0x7fffu + ((ul >> 16) & 1u)) >> 16;
    uh = (uh + 0x7fffu + ((uh >> 16) & 1u)) & 0xffff0000u;
    return uh | ul;
}
__device__ __forceinline__ float bf2f(short u) {
    return __uint_as_float(((unsigned)(unsigned short)u) << 16);
}

template<int CTRL>
__device__ __forceinline__ float dpp_add(float v) {
    int o = __builtin_amdgcn_mov_dpp(__float_as_int(v), CTRL, 0xf, 0xf, true);
    return v + __int_as_float(o);
}
// allreduce-sum across the 16-lane row group (row_ror 8,4,2,1)
__device__ __forceinline__ float row16_sum(float v) {
    v = dpp_add<0x128>(v);
    v = dpp_add<0x124>(v);
    v = dpp_add<0x122>(v);
    v = dpp_add<0x121>(v);
    return v;
}
// sum over thread-pair (lane ^ 1) via quad_perm [1,0,3,2]
__device__ __forceinline__ float pair_sum(float v) { return dpp_add<0xB1>(v); }
__device__ __forceinline__ float xor1(float v) {
    return __int_as_float(__builtin_amdgcn_mov_dpp(__float_as_int(v), 0xB1, 0xf, 0xf, true));
}

// stage BYTES from pre-swizzled global into LDS linearly (16B/lane async)
template<int BYTES>
__device__ __forceinline__ void stage_w(const char* gsrc, char* ldsdst, int t) {
    const int wu = (t >> 6) << 10;   // wave-uniform LDS base offset
#pragma unroll
    for (int i = 0; i < BYTES / 4096; ++i) {
        __builtin_amdgcn_global_load_lds(
            (const __attribute__((address_space(1))) void*)(gsrc + i * 4096 + t * 16),
            (__attribute__((address_space(3))) void*)(ldsdst + i * 4096 + wu),
            16, 0, 0);
    }
}

// ---- MFMA layer: acc[2][NF] over rows R0..R0+31, cols NF*16, K=128 ----
template<int NF>
__device__ __forceinline__ void init_acc(f32x4 acc[2][NF], const float* __restrict__ bias, int c) {
#pragma unroll
    for (int f = 0; f < NF; ++f) {
        const float bv = bias[f * 16 + c];
        acc[0][f] = (f32x4){bv, bv, bv, bv};
        acc[1][f] = (f32x4){bv, bv, bv, bv};
    }
}

template<int NF>
__device__ __forceinline__ void mfma_layer(const char* actb, const char* wb,
                                           int R0, int c, int g, f32x4 acc[2][NF]) {
    const int swz = (c & 7) << 4;
#pragma unroll
    for (int ks = 0; ks < 4; ++ks) {
        const int kb = ks * 64 + g * 16;
        bf16x8 A0 = *(const bf16x8*)(actb + (((R0 + c) * 256 + kb) ^ swz));
        bf16x8 A1 = *(const bf16x8*)(actb + (((R0 + 16 + c) * 256 + kb) ^ swz));
#pragma unroll
        for (int f = 0; f < NF; ++f) {
            bf16x8 B = *(const bf16x8*)(wb + (((f * 16 + c) * 256 + kb) ^ swz));
            acc[0][f] = __builtin_amdgcn_mfma_f32_16x16x32_bf16(A0, B, acc[0][f], 0, 0, 0);
            acc[1][f] = __builtin_amdgcn_mfma_f32_16x16x32_bf16(A1, B, acc[1][f], 0, 0, 0);
        }
    }
}

// LN(+g,b)+LeakyReLU on acc fragments; stats per row via in-lane + row16 allreduce
template<int NF>
__device__ __forceinline__ void ln_lrelu_frag(f32x4 acc[2][NF], int c,
                                              const float* __restrict__ g,
                                              const float* __restrict__ be, float invN) {
    float gv[NF], bev[NF];
#pragma unroll
    for (int f = 0; f < NF; ++f) { gv[f] = g[f * 16 + c]; bev[f] = be[f * 16 + c]; }
#pragma unroll
    for (int rf = 0; rf < 2; ++rf)
#pragma unroll
        for (int q = 0; q < 4; ++q) {
            float s1 = 0.f, s2 = 0.f;
#pragma unroll
            for (int f = 0; f < NF; ++f) { const float x = acc[rf][f][q]; s1 += x; s2 = fmaf(x, x, s2); }
            s1 = row16_sum(s1); s2 = row16_sum(s2);
            const float mu = s1 * invN;
            const float ri = rsqrtf(fmaf(s2, invN, -mu * mu) + 1e-5f);
#pragma unroll
            for (int f = 0; f < NF; ++f) {
                float x = (acc[rf][f][q] - mu) * ri;
                x = fmaf(x, gv[f], bev[f]);
                acc[rf][f][q] = fmaxf(x, 0.2f * x);
            }
        }
}

// pack C fragments to bf16 and write swizzled [rows][NF*16] tile (rowbytes = NF*32)
template<int NF>
__device__ __forceinline__ void pack_store(char* dst, int rowbytes, f32x4 acc[2][NF],
                                           int R0, int c, int g) {
    const int codd = c & 1;
    const int ceven = c & ~1;
#pragma unroll
    for (int rf = 0; rf < 2; ++rf)
#pragma unroll
        for (int q = 0; q < 4; ++q) {
            const int row = R0 + rf * 16 + g * 4 + q;
            const int rbase = row * rowbytes;
            const int swz = (row & 7) << 4;
#pragma unroll
            for (int m = 0; m < NF / 2; ++m) {
                const float a = acc[rf][2 * m][q];
                const float b = acc[rf][2 * m + 1][q];
                const float an = xor1(a), bn = xor1(b);
                const unsigned val = codd ? bfpack2(bn, b) : bfpack2(a, an);
                const int col0 = (2 * m + codd) * 16 + ceven;
                *(unsigned*)(dst + ((rbase + col0 * 2) ^ swz)) = val;
            }
        }
}

// per-thread-pair LN+lrelu+pack+swizzled store of 64 values (full row = 128)
__device__ __forceinline__ void ln_pair_store(float* v, char* dst, int r, int h,
                                              const float* __restrict__ g,
                                              const float* __restrict__ be) {
    float s1 = 0.f, s2 = 0.f;
#pragma unroll
    for (int j = 0; j < 64; ++j) { s1 += v[j]; s2 = fmaf(v[j], v[j], s2); }
    s1 = pair_sum(s1); s2 = pair_sum(s2);
    const float mu = s1 * (1.f / 128.f);
    const float ri = rsqrtf(fmaf(s2, 1.f / 128.f, -mu * mu) + 1e-5f);
    const int swz = (r & 7) << 4;
    const int rbase = r * 256 + h * 128;
#pragma unroll
    for (int u = 0; u < 32; ++u) {
        float a = (v[2 * u] - mu) * ri;
        a = fmaf(a, g[h * 64 + 2 * u], be[h * 64 + 2 * u]);
        a = fmaxf(a, 0.2f * a);
        float b = (v[2 * u + 1] - mu) * ri;
        b = fmaf(b, g[h * 64 + 2 * u + 1], be[h * 64 + 2 * u + 1]);
        b = fmaxf(b, 0.2f * b);
        *(unsigned*)(dst + ((rbase + 4 * u) ^ swz)) = bfpack2(a, b);
    }
}

// ---------------- prep kernels ----------------

__global__ void ce_precompute_kernel(const int* __restrict__ cats,
                                     const float* __restrict__ cat_emb,
                                     const float* __restrict__ cr_w1,
                                     const float* __restrict__ cr_b1,
                                     float* __restrict__ ce_out) {
    const int bb = blockIdx.x;
    const int j = threadIdx.x;            // 0..127
    const int c = cats[bb];
    float acc = cr_b1[j];
#pragma unroll 4
    for (int k = 0; k < 128; ++k)
        acc = fmaf(cat_emb[c * 128 + k], cr_w1[(128 + k) * 128 + j], acc);
    ce_out[bb * 128 + j] = acc;
}

// convert weights -> bf16, transposed [N][K], XOR-swizzled, into ws
__global__ void wconv_kernel(const float* __restrict__ pr_w2, const float* __restrict__ cr_w1,
                             const float* __restrict__ cr_w2, const float* __restrict__ sp_w2,
                             char* __restrict__ ws) {
    const int id = blockIdx.x * 256 + threadIdx.x;    // 0..61439
    float lo, hi;
    char* dst;
    if (id < 8192) {                       // pr2T: [128][128]
        const int n = id >> 6, kp = id & 63;
        lo = pr_w2[(2 * kp) * 128 + n]; hi = pr_w2[(2 * kp + 1) * 128 + n];
        dst = ws + 16384 + (((n << 8) + (kp << 2)) ^ ((n & 7) << 4));
    } else if (id < 16384) {               // cr1T: rows 0..127 of cr_w1
        const int i = id - 8192; const int n = i >> 6, kp = i & 63;
        lo = cr_w1[(2 * kp) * 128 + n]; hi = cr_w1[(2 * kp + 1) * 128 + n];
        dst = ws + 49152 + (((n << 8) + (kp << 2)) ^ ((n & 7) << 4));
    } else if (id < 20480) {               // cr2T: [64][128]
        const int i = id - 16384; const int n = i >> 6, kp = i & 63;
        lo = cr_w2[(2 * kp) * 64 + n]; hi = cr_w2[(2 * kp + 1) * 64 + n];
        dst = ws + 81920 + (((n << 8) + (kp << 2)) ^ ((n & 7) << 4));
    } else {                               // sp2T: [10][64][128]
        const int i = id - 20480; const int e = i >> 12; const int rr = i & 4095;
        const int n = rr >> 6, kp = rr & 63;
        lo = sp_w2[e * 8192 + (2 * kp) * 64 + n]; hi = sp_w2[e * 8192 + (2 * kp + 1) * 64 + n];
        dst = ws + 98304 + e * 16384 + (((n << 8) + (kp << 2)) ^ ((n & 7) << 4));
    }
    *(unsigned*)dst = bfpack2(lo, hi);
}

// ---------------- main fused kernel ----------------

__global__ __launch_bounds__(NT, 2)
void shape_refine_mfma(
    const float* __restrict__ points, const int* __restrict__ cats,
    const float* __restrict__ pr_w1, const float* __restrict__ pr_b1,
    const float* __restrict__ pr_g1, const float* __restrict__ pr_be1,
    const float* __restrict__ pr_b2, const float* __restrict__ pr_g2, const float* __restrict__ pr_be2,
    const float* __restrict__ cr_g1, const float* __restrict__ cr_be1,
    const float* __restrict__ cr_b2, const float* __restrict__ cr_g2, const float* __restrict__ cr_be2,
    const float* __restrict__ cr_w3, const float* __restrict__ cr_b3,
    const float* __restrict__ sy_w1, const float* __restrict__ sy_b1,
    const float* __restrict__ sy_g1, const float* __restrict__ sy_be1,
    const float* __restrict__ sy_w2, const float* __restrict__ sy_b2,
    const float* __restrict__ sp_w1, const float* __restrict__ sp_b1,
    const float* __restrict__ sp_g1, const float* __restrict__ sp_be1,
    const float* __restrict__ sp_b2, const float* __restrict__ sp_g2, const float* __restrict__ sp_be2,
    const float* __restrict__ sp_w3, const float* __restrict__ sp_b3,
    const char* __restrict__ ws,
    float* __restrict__ out)
{
    __shared__ char act[32768];    // bf16 [128 rows][128 cols], XOR-swizzled
    __shared__ char wbuf[32768];   // staged weights (lo 16K / hi 16K doubles as act64)
    char* wbhi = wbuf + 16384;

    const int t = threadIdx.x;
    const int lane = t & 63;
    const int wid = t >> 6;
    const int c = lane & 15;
    const int g = lane >> 4;
    const int R0 = wid * 32;

    int bid = blockIdx.x;
    bid = (bid & 7) * 64 + (bid >> 3);          // XCD swizzle (512 = 8*64, bijective)
    const int batch = bid >> 4;
    const int bib = bid & 15;

    const int cat = __builtin_amdgcn_readfirstlane(cats[batch]);
    const bool sym = (cat == 2) || (cat == 8);

    const float* ce = (const float*)ws + batch * 128;
    const char* pr2T = ws + 16384;
    const char* cr1T = ws + 49152;
    const char* cr2T = ws + 81920;
    const char* sp2T = ws + 98304 + cat * 16384;

    const int r = t >> 1;     // per-thread-pair row (0..127)
    const int h = t & 1;

    for (int it = 0; it < 4; ++it) {
        const int tile = bib * 4 + it;
        const int pbase = batch * 8192 + tile * 128;

        const float x0 = points[3 * (pbase + r) + 0];
        const float x1 = points[3 * (pbase + r) + 1];
        const float x2 = points[3 * (pbase + r) + 2];

        // phase 0: async-stage pr2 weights
        stage_w<32768>(pr2T, wbuf, t);

        // phase 1: pr1 (3->128) per-thread-pair
        {
            float v[64];
            const float* w0 = pr_w1 + h * 64;
#pragma unroll
            for (int j = 0; j < 64; ++j)
                v[j] = fmaf(x0, w0[j], fmaf(x1, w0[128 + j], fmaf(x2, w0[256 + j], pr_b1[h * 64 + j])));
            ln_pair_store(v, act, r, h, pr_g1, pr_be1);
        }
        __syncthreads();                         // act ready, pr2W staged (vmcnt0)

        // phase 2: pr2 (128->128) MFMA
        {
            f32x4 acc[2][8];
            init_acc<8>(acc, pr_b2, c);
            mfma_layer<8>(act, wbuf, R0, c, g, acc);
            __syncthreads();                     // all wbuf reads done
            stage_w<32768>(cr1T, wbuf, t);
            ln_lrelu_frag<8>(acc, c, pr_g2, pr_be2, 1.f / 128.f);
            pack_store<8>(act, 256, acc, R0, c, g);
        }
        __syncthreads();

        // phase 3: cr1 (256->128, embedding folded into per-batch bias)
        {
            f32x4 acc[2][8];
            init_acc<8>(acc, ce, c);
            mfma_layer<8>(act, wbuf, R0, c, g, acc);
            __syncthreads();
            stage_w<16384>(cr2T, wbuf, t);
            ln_lrelu_frag<8>(acc, c, cr_g1, cr_be1, 1.f / 128.f);
            pack_store<8>(act, 256, acc, R0, c, g);
        }
        __syncthreads();

        // phase 4: cr2 (128->64) MFMA, result act64 -> wbuf-hi
        {
            f32x4 acc[2][4];
            init_acc<4>(acc, cr_b2, c);
            mfma_layer<4>(act, wbuf, R0, c, g, acc);
            ln_lrelu_frag<4>(acc, c, cr_g2, cr_be2, 1.f / 64.f);
            pack_store<4>(wbhi, 128, acc, R0, c, g);
        }
        __syncthreads();
        stage_w<16384>(sp2T, wbuf, t);

        // phase 5: cr3 (64->3) per-thread-pair + sp1 (3->128) per-thread-pair
        float o0, o1, o2;
        {
            float p0 = 0.f, p1 = 0.f, p2 = 0.f;
            const int swz = (r & 7) << 4;
#pragma unroll
            for (int i = 0; i < 4; ++i) {
                bf16x8 vv = *(const bf16x8*)(wbhi + ((r * 128 + h * 64 + i * 16) ^ swz));
#pragma unroll
                for (int e = 0; e < 8; ++e) {
                    const int k = h * 32 + i * 8 + e;
                    const float f = bf2f(vv[e]);
                    p0 = fmaf(f, cr_w3[k * 3 + 0], p0);
                    p1 = fmaf(f, cr_w3[k * 3 + 1], p1);
                    p2 = fmaf(f, cr_w3[k * 3 + 2], p2);
                }
            }
            o0 = pair_sum(p0) + cr_b3[0];
            o1 = pair_sum(p1) + cr_b3[1];
            o2 = pair_sum(p2) + cr_b3[2];
        }
        {
            float v[64];
            const float* w0 = sp_w1 + cat * 384 + h * 64;
            const float* b0 = sp_b1 + cat * 128 + h * 64;
#pragma unroll
            for (int j = 0; j < 64; ++j)
                v[j] = fmaf(x0, w0[j], fmaf(x1, w0[128 + j], fmaf(x2, w0[256 + j], b0[j])));
            ln_pair_store(v, act, r, h, sp_g1 + cat * 128, sp_be1 + cat * 128);
        }
        __syncthreads();                         // sp1 act visible, sp2W staged

        // phase 6: sp2 (128->64) MFMA, result act64 -> wbuf-hi
        {
            f32x4 acc[2][4];
            init_acc<4>(acc, sp_b2 + cat * 64, c);
            mfma_layer<4>(act, wbuf, R0, c, g, acc);
            ln_lrelu_frag<4>(acc, c, sp_g2 + cat * 64, sp_be2 + cat * 64, 1.f / 64.f);
            pack_store<4>(wbhi, 128, acc, R0, c, g);
        }
        __syncthreads();

        // phase 7: sp3 (64->3) + symmetry + store
        {
            float p0 = 0.f, p1 = 0.f, p2 = 0.f;
            const int swz = (r & 7) << 4;
            const float* w3 = sp_w3 + cat * 192;
#pragma unroll
            for (int i = 0; i < 4; ++i) {
                bf16x8 vv = *(const bf16x8*)(wbhi + ((r * 128 + h * 64 + i * 16) ^ swz));
#pragma unroll
                for (int e = 0; e < 8; ++e) {
                    const int k = h * 32 + i * 8 + e;
                    const float f = bf2f(vv[e]);
                    p0 = fmaf(f, w3[k * 3 + 0], p0);
                    p1 = fmaf(f, w3[k * 3 + 1], p1);
                    p2 = fmaf(f, w3[k * 3 + 2], p2);
                }
            }
            p0 = pair_sum(p0) + sp_b3[cat * 3 + 0];
            p1 = pair_sum(p1) + sp_b3[cat * 3 + 1];
            p2 = pair_sum(p2) + sp_b3[cat * 3 + 2];
            o0 = fmaf(0.5f, p0, o0);
            o1 = fmaf(0.5f, p1, o1);
            o2 = fmaf(0.5f, p2, o2);
        }
        if (sym) {
            float v[32];
            const float m0 = -x0;
#pragma unroll
            for (int j = 0; j < 32; ++j) {
                const int jj = h * 32 + j;
                v[j] = fmaf(m0, sy_w1[jj], fmaf(x1, sy_w1[64 + jj], fmaf(x2, sy_w1[128 + jj], sy_b1[jj])));
            }
            float s1 = 0.f, s2 = 0.f;
#pragma unroll
            for (int j = 0; j < 32; ++j) { s1 += v[j]; s2 = fmaf(v[j], v[j], s2); }
            s1 = pair_sum(s1); s2 = pair_sum(s2);
            const float mu = s1 * (1.f / 64.f);
            const float ri = rsqrtf(fmaf(s2, 1.f / 64.f, -mu * mu) + 1e-5f);
            float t0 = 0.f, t1 = 0.f, t2 = 0.f;
#pragma unroll
            for (int j = 0; j < 32; ++j) {
                const int jj = h * 32 + j;
                float y = (v[j] - mu) * ri;
                y = fmaf(y, sy_g1[jj], sy_be1[jj]);
                y = fmaxf(y, 0.2f * y);
                t0 = fmaf(y, sy_w2[jj * 3 + 0], t0);
                t1 = fmaf(y, sy_w2[jj * 3 + 1], t1);
                t2 = fmaf(y, sy_w2[jj * 3 + 2], t2);
            }
            t0 = pair_sum(t0) + sy_b2[0];
            t1 = pair_sum(t1) + sy_b2[1];
            t2 = pair_sum(t2) + sy_b2[2];
            o0 = (o0 - t0) * 0.5f;     // flip on output dim 0
            o1 = (o1 + t1) * 0.5f;
            o2 = (o2 + t2) * 0.5f;
        }
        if (h == 0) {
            out[3 * (pbase + r) + 0] = o0;
            out[3 * (pbase + r) + 1] = o1;
            out[3 * (pbase + r) + 2] = o2;
        }
        __syncthreads();   // protect act/wbuf before next iteration's staging
    }
}

// ---------------- launch ----------------

extern "C" void kernel_launch(void* const* d_in, const int* in_sizes, int n_in,
                              void* d_out, int out_size, void* d_ws, size_t ws_size,
                              hipStream_t stream) {
    const float* points  = (const float*)d_in[0];
    const int*   cats    = (const int*)  d_in[1];
    const float* pr_w1   = (const float*)d_in[2];
    const float* pr_b1   = (const float*)d_in[3];
    const float* pr_g1   = (const float*)d_in[4];
    const float* pr_be1  = (const float*)d_in[5];
    const float* pr_w2   = (const float*)d_in[6];
    const float* pr_b2   = (const float*)d_in[7];
    const float* pr_g2   = (const float*)d_in[8];
    const float* pr_be2  = (const float*)d_in[9];
    const float* cat_emb = (const float*)d_in[10];
    const float* cr_w1   = (const float*)d_in[11];
    const float* cr_b1   = (const float*)d_in[12];
    const float* cr_g1   = (const float*)d_in[13];
    const float* cr_be1  = (const float*)d_in[14];
    const float* cr_w2   = (const float*)d_in[15];
    const float* cr_b2   = (const float*)d_in[16];
    const float* cr_g2   = (const float*)d_in[17];
    const float* cr_be2  = (const float*)d_in[18];
    const float* cr_w3   = (const float*)d_in[19];
    const float* cr_b3   = (const float*)d_in[20];
    const float* sy_w1   = (const float*)d_in[21];
    const float* sy_b1   = (const float*)d_in[22];
    const float* sy_g1   = (const float*)d_in[23];
    const float* sy_be1  = (const float*)d_in[24];
    const float* sy_w2   = (const float*)d_in[25];
    const float* sy_b2   = (const float*)d_in[26];
    const float* sp_w1   = (const float*)d_in[27];
    const float* sp_b1   = (const float*)d_in[28];
    const float* sp_g1   = (const float*)d_in[29];
    const float* sp_be1  = (const float*)d_in[30];
    const float* sp_w2   = (const float*)d_in[31];
    const float* sp_b2   = (const float*)d_in[32];
    const float* sp_g2   = (const float*)d_in[33];
    const float* sp_be2  = (const float*)d_in[34];
    const float* sp_w3   = (const float*)d_in[35];
    const float* sp_b3   = (const float*)d_in[36];

    char* ws = (char*)d_ws;      // layout: ce 16K | pr2T 32K | cr1T 32K | cr2T 16K | sp2T 160K
    float* out = (float*)d_out;

    ce_precompute_kernel<<<dim3(32), dim3(128), 0, stream>>>(cats, cat_emb, cr_w1, cr_b1, (float*)ws);
    wconv_kernel<<<dim3(240), dim3(256), 0, stream>>>(pr_w2, cr_w1, cr_w2, sp_w2, ws);

    shape_refine_mfma<<<dim3(512), dim3(NT), 0, stream>>>(
        points, cats,
        pr_w1, pr_b1, pr_g1, pr_be1,
        pr_b2, pr_g2, pr_be2,
        cr_g1, cr_be1,
        cr_b2, cr_g2, cr_be2,
        cr_w3, cr_b3,
        sy_w1, sy_b1, sy_g1, sy_be1,
        sy_w2, sy_b2,
        sp_w1, sp_b1, sp_g1, sp_be1,
        sp_b2, sp_g2, sp_be2,
        sp_w3, sp_b3,
        ws, out);
}

// Round 3
// 203.560 us; speedup vs baseline: 5.8978x; 5.8978x over previous
//
#include <hip/hip_runtime.h>
#include <hip/hip_bf16.h>
#include <stdint.h>

typedef __attribute__((ext_vector_type(8))) short bf16x8;
typedef __attribute__((ext_vector_type(4))) float f32x4;

#define NT 256

// ---------------- ws layout (bytes) ----------------
// 0       : ce bias      (32*128 f32)               16384
// 16384   : pr1F  (KS=1, NF=8)                       8192
// 24576   : pr2F  (KS=4, NF=8)                      32768
// 57344   : cr1F  (KS=4, NF=8)                      32768
// 90112   : cr2F  (KS=4, NF=4)                      16384
// 106496  : cr3F  (KS=2, NF=1)                       2048
// 108544  : sy1F  (KS=1, NF=4)                       4096
// 112640  : sy2F  (KS=2, NF=1)                       2048
// 114688  : sp1F  [10] (KS=1, NF=8)                 81920
// 196608  : sp2F  [10] (KS=4, NF=4)                163840
// 360448  : sp3F  [10] (KS=2, NF=1)                 20480
// total 380928

#define WS_CE    0
#define WS_PR1   16384
#define WS_PR2   24576
#define WS_CR1   57344
#define WS_CR2   90112
#define WS_CR3   106496
#define WS_SY1   108544
#define WS_SY2   112640
#define WS_SP1   114688
#define WS_SP2   196608
#define WS_SP3   360448

// ---------------- helpers ----------------

__device__ __forceinline__ unsigned bfpack2(float lo, float hi) {
    unsigned ul = __float_as_uint(lo);
    unsigned uh = __float_as_uint(hi);
    ul = (ul + 0x7fffu + ((ul >> 16) & 1u)) >> 16;
    uh = (uh + 0x7fffu + ((uh >> 16) & 1u)) & 0xffff0000u;
    return uh | ul;
}
__device__ __forceinline__ short bf1(float x) {
    unsigned u = __float_as_uint(x);
    return (short)((u + 0x7fffu + ((u >> 16) & 1u)) >> 16);
}
__device__ __forceinline__ float bfval(short h) {
    return __uint_as_float(((unsigned)(unsigned short)h) << 16);
}

template<int CTRL>
__device__ __forceinline__ float dpp_add(float v) {
    int o = __builtin_amdgcn_mov_dpp(__float_as_int(v), CTRL, 0xf, 0xf, true);
    return v + __int_as_float(o);
}
__device__ __forceinline__ float row16_sum(float v) {
    v = dpp_add<0x128>(v);
    v = dpp_add<0x124>(v);
    v = dpp_add<0x122>(v);
    v = dpp_add<0x121>(v);
    return v;
}
__device__ __forceinline__ float xor1(float v) {
    return __int_as_float(__builtin_amdgcn_mov_dpp(__float_as_int(v), 0xB1, 0xf, 0xf, true));
}

// ---- accumulator init ----
template<int NF>
__device__ __forceinline__ void init_acc(f32x4 acc[2][NF], const float* __restrict__ bias, int c) {
#pragma unroll
    for (int f = 0; f < NF; ++f) {
        const float bv = bias[f * 16 + c];
        acc[0][f] = (f32x4){bv, bv, bv, bv};
        acc[1][f] = (f32x4){bv, bv, bv, bv};
    }
}
__device__ __forceinline__ void init_b3(f32x4 acc[2], const float* __restrict__ b3, int c) {
    const float bv = (c < 3) ? b3[c] : 0.f;
    acc[0] = (f32x4){bv, bv, bv, bv};
    acc[1] = (f32x4){bv, bv, bv, bv};
}

// ---- A fragment from xyz registers (k=0..2 hi, k=3..5 lo) ----
__device__ __forceinline__ bf16x8 mkA6(float a0, float a1, float a2, bool active) {
    bf16x8 A = (bf16x8){0, 0, 0, 0, 0, 0, 0, 0};
    if (active) {
        const short h0 = bf1(a0), h1 = bf1(a1), h2 = bf1(a2);
        A[0] = h0; A[1] = h1; A[2] = h2;
        A[3] = bf1(a0 - bfval(h0));
        A[4] = bf1(a1 - bfval(h1));
        A[5] = bf1(a2 - bfval(h2));
    }
    return A;
}

// ---- MFMA with A from registers (single K-step), B frags from global ----
template<int NF>
__device__ __forceinline__ void mfma_reg(bf16x8 A0, bf16x8 A1, const char* __restrict__ Bg,
                                         int lane, f32x4 acc[2][NF]) {
#pragma unroll
    for (int f = 0; f < NF; ++f) {
        bf16x8 B = *(const bf16x8*)(Bg + f * 1024 + lane * 16);
        acc[0][f] = __builtin_amdgcn_mfma_f32_16x16x32_bf16(A0, B, acc[0][f], 0, 0, 0);
        acc[1][f] = __builtin_amdgcn_mfma_f32_16x16x32_bf16(A1, B, acc[1][f], 0, 0, 0);
    }
}

// ---- MFMA with A from LDS act tile (rows R0c, R0c+16), B frags from global ----
template<int NF, int KS>
__device__ __forceinline__ void mfma_lds(const char* actb, const char* __restrict__ Bg,
                                         int R0c, int g, int lane, f32x4 acc[2][NF]) {
    const int swz = (R0c & 7) << 4;
#pragma unroll
    for (int ks = 0; ks < KS; ++ks) {
        const int kb = ks * 64 + g * 16;
        bf16x8 A0 = *(const bf16x8*)(actb + ((R0c * 256 + kb) ^ swz));
        bf16x8 A1 = *(const bf16x8*)(actb + (((R0c + 16) * 256 + kb) ^ swz));
#pragma unroll
        for (int f = 0; f < NF; ++f) {
            bf16x8 B = *(const bf16x8*)(Bg + (f * KS + ks) * 1024 + lane * 16);
            acc[0][f] = __builtin_amdgcn_mfma_f32_16x16x32_bf16(A0, B, acc[0][f], 0, 0, 0);
            acc[1][f] = __builtin_amdgcn_mfma_f32_16x16x32_bf16(A1, B, acc[1][f], 0, 0, 0);
        }
    }
}

// ---- LayerNorm + LeakyReLU on C fragments (row stats via 16-lane DPP allreduce) ----
template<int NF>
__device__ __forceinline__ void ln_lrelu_frag(f32x4 acc[2][NF], int c,
                                              const float* __restrict__ g,
                                              const float* __restrict__ be, float invN) {
    float gv[NF], bev[NF];
#pragma unroll
    for (int f = 0; f < NF; ++f) { gv[f] = g[f * 16 + c]; bev[f] = be[f * 16 + c]; }
#pragma unroll
    for (int rf = 0; rf < 2; ++rf)
#pragma unroll
        for (int q = 0; q < 4; ++q) {
            float s1 = 0.f, s2 = 0.f;
#pragma unroll
            for (int f = 0; f < NF; ++f) { const float x = acc[rf][f][q]; s1 += x; s2 = fmaf(x, x, s2); }
            s1 = row16_sum(s1); s2 = row16_sum(s2);
            const float mu = s1 * invN;
            const float ri = rsqrtf(fmaf(s2, invN, -mu * mu) + 1e-5f);
#pragma unroll
            for (int f = 0; f < NF; ++f) {
                float x = (acc[rf][f][q] - mu) * ri;
                x = fmaf(x, gv[f], bev[f]);
                acc[rf][f][q] = fmaxf(x, 0.2f * x);
            }
        }
}

// ---- pack C fragments to bf16 act tile (row-major 256B rows, XOR swizzle) ----
template<int NF>
__device__ __forceinline__ void pack_store(char* dst, f32x4 acc[2][NF], int R0, int c, int g) {
    const int codd = c & 1;
    const int ceven = c & ~1;
#pragma unroll
    for (int rf = 0; rf < 2; ++rf)
#pragma unroll
        for (int q = 0; q < 4; ++q) {
            const int row = R0 + rf * 16 + g * 4 + q;
            const int rbase = row * 256;
            const int swz = (row & 7) << 4;
#pragma unroll
            for (int m = 0; m < NF / 2; ++m) {
                const float a = acc[rf][2 * m][q];
                const float b = acc[rf][2 * m + 1][q];
                const float an = xor1(a), bn = xor1(b);
                const unsigned val = codd ? bfpack2(bn, b) : bfpack2(a, an);
                const int col0 = (2 * m + codd) * 16 + ceven;
                *(unsigned*)(dst + ((rbase + col0 * 2) ^ swz)) = val;
            }
        }
}

// ---------------- prep kernels ----------------

__global__ void ce_precompute_kernel(const int* __restrict__ cats,
                                     const float* __restrict__ cat_emb,
                                     const float* __restrict__ cr_w1,
                                     const float* __restrict__ cr_b1,
                                     float* __restrict__ ce_out) {
    const int bb = blockIdx.x;
    const int j = threadIdx.x;            // 0..127
    const int c = cats[bb];
    float acc = cr_b1[j];
#pragma unroll 4
    for (int k = 0; k < 128; ++k)
        acc = fmaf(cat_emb[c * 128 + k], cr_w1[(128 + k) * 128 + j], acc);
    ce_out[bb * 128 + j] = acc;
}

// build all B-fragments (bf16, frag layout [(f*KS+ks)*64+lane]*16B) into ws
__global__ void wfrag_kernel(
    const float* __restrict__ pr_w1, const float* __restrict__ pr_w2,
    const float* __restrict__ cr_w1, const float* __restrict__ cr_w2,
    const float* __restrict__ cr_w3, const float* __restrict__ sy_w1,
    const float* __restrict__ sy_w2, const float* __restrict__ sp_w1,
    const float* __restrict__ sp_w2, const float* __restrict__ sp_w3,
    char* __restrict__ ws)
{
    const int id = blockIdx.x * 256 + threadIdx.x;   // 0..22783 frag-lanes
    int local, KS, base, cat = 0;
    const float* W = nullptr;
    int mode;   // 0: k<6 dup (3->N), 1: dense KxN, 2: n<3 (K->3)
    int Nstride = 0;

    if (id < 512)        { local = id;          KS = 1; base = WS_PR1; W = pr_w1; mode = 0; Nstride = 128; }
    else if (id < 2560)  { local = id - 512;    KS = 4; base = WS_PR2; W = pr_w2; mode = 1; Nstride = 128; }
    else if (id < 4608)  { local = id - 2560;   KS = 4; base = WS_CR1; W = cr_w1; mode = 1; Nstride = 128; }
    else if (id < 5632)  { local = id - 4608;   KS = 4; base = WS_CR2; W = cr_w2; mode = 1; Nstride = 64; }
    else if (id < 5760)  { local = id - 5632;   KS = 2; base = WS_CR3; W = cr_w3; mode = 2; }
    else if (id < 6016)  { local = id - 5760;   KS = 1; base = WS_SY1; W = sy_w1; mode = 0; Nstride = 64; }
    else if (id < 6144)  { local = id - 6016;   KS = 2; base = WS_SY2; W = sy_w2; mode = 2; }
    else if (id < 11264) { int r = id - 6144;  cat = r / 512;  local = r % 512;
                           KS = 1; base = WS_SP1 + cat * 8192;  W = sp_w1 + cat * 384;  mode = 0; Nstride = 128; }
    else if (id < 21504) { int r = id - 11264; cat = r / 1024; local = r % 1024;
                           KS = 4; base = WS_SP2 + cat * 16384; W = sp_w2 + cat * 8192; mode = 1; Nstride = 64; }
    else                 { int r = id - 21504; cat = r / 128;  local = r % 128;
                           KS = 2; base = WS_SP3 + cat * 2048;  W = sp_w3 + cat * 192;  mode = 2; }

    const int lane = local & 63;
    const int fk = local >> 6;
    const int ks = fk % KS;
    const int f = fk / KS;
    const int c = lane & 15;
    const int g = lane >> 4;
    const int n = f * 16 + c;
    const int k0 = ks * 32 + g * 8;

    bf16x8 H;
#pragma unroll
    for (int e = 0; e < 8; ++e) {
        const int k = k0 + e;
        float v = 0.f;
        if (mode == 0)      { if (k < 6) v = W[(k < 3 ? k : k - 3) * Nstride + n]; }
        else if (mode == 1) { v = W[k * Nstride + n]; }
        else                { if (n < 3) v = W[k * 3 + n]; }
        H[e] = bf1(v);
    }
    *(bf16x8*)(ws + base + local * 16) = H;
}

// ---------------- main fused kernel ----------------

__global__ __launch_bounds__(NT, 4)
void shape_refine_mfma2(
    const float* __restrict__ points, const int* __restrict__ cats,
    const float* __restrict__ pr_b1, const float* __restrict__ pr_g1, const float* __restrict__ pr_be1,
    const float* __restrict__ pr_b2, const float* __restrict__ pr_g2, const float* __restrict__ pr_be2,
    const float* __restrict__ cr_g1, const float* __restrict__ cr_be1,
    const float* __restrict__ cr_b2, const float* __restrict__ cr_g2, const float* __restrict__ cr_be2,
    const float* __restrict__ cr_b3,
    const float* __restrict__ sy_b1, const float* __restrict__ sy_g1, const float* __restrict__ sy_be1,
    const float* __restrict__ sy_b2,
    const float* __restrict__ sp_b1, const float* __restrict__ sp_g1, const float* __restrict__ sp_be1,
    const float* __restrict__ sp_b2, const float* __restrict__ sp_g2, const float* __restrict__ sp_be2,
    const float* __restrict__ sp_b3,
    const char* __restrict__ ws,
    float* __restrict__ out)
{
    __shared__ char act[32768];    // bf16 [128 rows][128 cols], 256B rows, XOR-swizzled

    const int t = threadIdx.x;
    const int lane = t & 63;
    const int wid = t >> 6;
    const int c = lane & 15;
    const int g = lane >> 4;
    const int R0 = wid * 32;
    const int R0c = R0 + c;

    const int bid = blockIdx.x;
    const int batch = bid >> 6;              // 64 blocks (tiles) per batch
    const int pbase = batch * 8192 + (bid & 63) * 128;

    const int cat = __builtin_amdgcn_readfirstlane(cats[batch]);
    const bool sym = (cat == 2) || (cat == 8);

    // xyz for this lane's two A-rows
    const float* p0 = points + 3 * (pbase + R0c);
    const float x0 = p0[0], x1 = p0[1], x2 = p0[2];
    const float y0 = p0[48], y1 = p0[49], y2 = p0[50];   // row +16 -> +48 floats

    const bf16x8 A0 = mkA6(x0, x1, x2, g == 0);
    const bf16x8 A1 = mkA6(y0, y1, y2, g == 0);

    f32x4 acc8[2][8];
    f32x4 acc4[2][4];
    f32x4 ocr[2], o2[2];

    // ---- P1: pr1 (3->128) from registers ----
    init_acc<8>(acc8, pr_b1, c);
    mfma_reg<8>(A0, A1, ws + WS_PR1, lane, acc8);
    ln_lrelu_frag<8>(acc8, c, pr_g1, pr_be1, 1.f / 128.f);
    pack_store<8>(act, acc8, R0, c, g);
    __syncthreads();

    // ---- P2: pr2 (128->128) ----
    init_acc<8>(acc8, pr_b2, c);
    mfma_lds<8, 4>(act, ws + WS_PR2, R0c, g, lane, acc8);
    __syncthreads();
    ln_lrelu_frag<8>(acc8, c, pr_g2, pr_be2, 1.f / 128.f);
    pack_store<8>(act, acc8, R0, c, g);
    __syncthreads();

    // ---- P3: cr1 (256->128, cat-emb folded into per-batch bias) ----
    init_acc<8>(acc8, (const float*)(ws + WS_CE) + batch * 128, c);
    mfma_lds<8, 4>(act, ws + WS_CR1, R0c, g, lane, acc8);
    __syncthreads();
    ln_lrelu_frag<8>(acc8, c, cr_g1, cr_be1, 1.f / 128.f);
    pack_store<8>(act, acc8, R0, c, g);
    __syncthreads();

    // ---- P4: cr2 (128->64) ----
    init_acc<4>(acc4, cr_b2, c);
    mfma_lds<4, 4>(act, ws + WS_CR2, R0c, g, lane, acc4);
    __syncthreads();
    ln_lrelu_frag<4>(acc4, c, cr_g2, cr_be2, 1.f / 64.f);
    pack_store<4>(act, acc4, R0, c, g);
    __syncthreads();

    // ---- P5: cr3 (64->3) + sp1 (3->128) ----
    init_b3(ocr, cr_b3, c);
    {
        f32x4 a1[2][1] = {{ocr[0]}, {ocr[1]}};
        mfma_lds<1, 2>(act, ws + WS_CR3, R0c, g, lane, a1);
        ocr[0] = a1[0][0]; ocr[1] = a1[1][0];
    }
    init_acc<8>(acc8, sp_b1 + cat * 128, c);
    mfma_reg<8>(A0, A1, ws + WS_SP1 + cat * 8192, lane, acc8);
    ln_lrelu_frag<8>(acc8, c, sp_g1 + cat * 128, sp_be1 + cat * 128, 1.f / 128.f);
    __syncthreads();                 // cr3's act reads done everywhere
    pack_store<8>(act, acc8, R0, c, g);
    __syncthreads();

    // ---- P6: sp2 (128->64) ----
    init_acc<4>(acc4, sp_b2 + cat * 64, c);
    mfma_lds<4, 4>(act, ws + WS_SP2 + cat * 16384, R0c, g, lane, acc4);
    __syncthreads();
    ln_lrelu_frag<4>(acc4, c, sp_g2 + cat * 64, sp_be2 + cat * 64, 1.f / 64.f);
    pack_store<4>(act, acc4, R0, c, g);
    __syncthreads();

    // ---- P7: sp3 (64->3), combine ----
    {
        f32x4 a1[2][1];
        init_b3(o2, sp_b3 + cat * 3, c);
        a1[0][0] = o2[0]; a1[1][0] = o2[1];
        mfma_lds<1, 2>(act, ws + WS_SP3 + cat * 2048, R0c, g, lane, a1);
        o2[0] = ocr[0] + 0.5f * a1[0][0];
        o2[1] = ocr[1] + 0.5f * a1[1][0];
    }

    // ---- symmetry branch (block-uniform) ----
    if (sym) {
        __syncthreads();             // sp3's act reads done
        f32x4 accS[2][4];
        init_acc<4>(accS, sy_b1, c);
        const bf16x8 S0 = mkA6(-x0, x1, x2, g == 0);
        const bf16x8 S1 = mkA6(-y0, y1, y2, g == 0);
        mfma_reg<4>(S0, S1, ws + WS_SY1, lane, accS);
        ln_lrelu_frag<4>(accS, c, sy_g1, sy_be1, 1.f / 64.f);
        pack_store<4>(act, accS, R0, c, g);
        __syncthreads();
        f32x4 a1[2][1];
        init_b3(a1[0], sy_b2, c);    // a1[0][0], then copy
        a1[1][0] = a1[0][0];
        mfma_lds<1, 2>(act, ws + WS_SY2, R0c, g, lane, a1);
        const float flip = (c == 0) ? -1.f : 1.f;
#pragma unroll
        for (int rf = 0; rf < 2; ++rf)
#pragma unroll
            for (int q = 0; q < 4; ++q)
                o2[rf][q] = (o2[rf][q] + flip * a1[rf][0][q]) * 0.5f;
    }

    // ---- store: lane c<3 holds dim c for rows R0 + rf*16 + g*4 + q ----
    if (c < 3) {
#pragma unroll
        for (int rf = 0; rf < 2; ++rf)
#pragma unroll
            for (int q = 0; q < 4; ++q) {
                const int row = R0 + rf * 16 + g * 4 + q;
                out[3 * (pbase + row) + c] = o2[rf][q];
            }
    }
}

// ---------------- launch ----------------

extern "C" void kernel_launch(void* const* d_in, const int* in_sizes, int n_in,
                              void* d_out, int out_size, void* d_ws, size_t ws_size,
                              hipStream_t stream) {
    const float* points  = (const float*)d_in[0];
    const int*   cats    = (const int*)  d_in[1];
    const float* pr_w1   = (const float*)d_in[2];
    const float* pr_b1   = (const float*)d_in[3];
    const float* pr_g1   = (const float*)d_in[4];
    const float* pr_be1  = (const float*)d_in[5];
    const float* pr_w2   = (const float*)d_in[6];
    const float* pr_b2   = (const float*)d_in[7];
    const float* pr_g2   = (const float*)d_in[8];
    const float* pr_be2  = (const float*)d_in[9];
    const float* cat_emb = (const float*)d_in[10];
    const float* cr_w1   = (const float*)d_in[11];
    const float* cr_b1   = (const float*)d_in[12];
    const float* cr_g1   = (const float*)d_in[13];
    const float* cr_be1  = (const float*)d_in[14];
    const float* cr_w2   = (const float*)d_in[15];
    const float* cr_b2   = (const float*)d_in[16];
    const float* cr_g2   = (const float*)d_in[17];
    const float* cr_be2  = (const float*)d_in[18];
    const float* cr_w3   = (const float*)d_in[19];
    const float* cr_b3   = (const float*)d_in[20];
    const float* sy_w1   = (const float*)d_in[21];
    const float* sy_b1   = (const float*)d_in[22];
    const float* sy_g1   = (const float*)d_in[23];
    const float* sy_be1  = (const float*)d_in[24];
    const float* sy_w2   = (const float*)d_in[25];
    const float* sy_b2   = (const float*)d_in[26];
    const float* sp_w1   = (const float*)d_in[27];
    const float* sp_b1   = (const float*)d_in[28];
    const float* sp_g1   = (const float*)d_in[29];
    const float* sp_be1  = (const float*)d_in[30];
    const float* sp_w2   = (const float*)d_in[31];
    const float* sp_b2   = (const float*)d_in[32];
    const float* sp_g2   = (const float*)d_in[33];
    const float* sp_be2  = (const float*)d_in[34];
    const float* sp_w3   = (const float*)d_in[35];
    const float* sp_b3   = (const float*)d_in[36];

    char* ws = (char*)d_ws;
    float* out = (float*)d_out;

    ce_precompute_kernel<<<dim3(32), dim3(128), 0, stream>>>(cats, cat_emb, cr_w1, cr_b1, (float*)ws);
    wfrag_kernel<<<dim3(89), dim3(256), 0, stream>>>(pr_w1, pr_w2, cr_w1, cr_w2, cr_w3,
                                                     sy_w1, sy_w2, sp_w1, sp_w2, sp_w3, ws);

    shape_refine_mfma2<<<dim3(2048), dim3(NT), 0, stream>>>(
        points, cats,
        pr_b1, pr_g1, pr_be1,
        pr_b2, pr_g2, pr_be2,
        cr_g1, cr_be1,
        cr_b2, cr_g2, cr_be2,
        cr_b3,
        sy_b1, sy_g1, sy_be1, sy_b2,
        sp_b1, sp_g1, sp_be1,
        sp_b2, sp_g2, sp_be2,
        sp_b3,
        ws, out);
}